// Round 1
// baseline (130.915 us; speedup 1.0000x reference)
//
#include <hip/hip_runtime.h>
#include <hip/hip_bf16.h>

// Performer FAVOR+ causal attention, MI355X gfx950.
// B=4 H=16 S=1024 D=64 M=64. fp32 in/out, bf16 MFMA internally.

#define S_LEN 1024
#define NHEADS 64          // B*H
#define NRM 0.35355339059327373f   // 64^-0.25
#define EPSF 1e-4f

typedef __attribute__((ext_vector_type(8))) short short8;
typedef __attribute__((ext_vector_type(4))) float f32x4;
typedef unsigned short u16;

__device__ inline u16 f2bf(float f) {
    unsigned u = __float_as_uint(f);
    unsigned r = u + 0x7FFFu + ((u >> 16) & 1u);   // RNE
    return (u16)(r >> 16);
}

__device__ inline void atomicMaxF(float* a, float v) {
    if (v >= 0.f) atomicMax((int*)a, __float_as_int(v));
    else          atomicMin((unsigned int*)a, (unsigned int)__float_as_int(v));
}

__global__ void init_hm(float* hm) { hm[threadIdx.x] = -INFINITY; }

// ---------------------------------------------------------------------------
// Feature map: dd[row][m] = NRM * (x[row][:] @ P[:, m])
// MODE 0: qp = exp(dd - diag - rowmax) + eps          (per-row stab)
// MODE 1: headmax[bh] = atomicMax over rows of max_m dd (per-head stab)
// MODE 2: kp = exp(dd - diag - headmax[bh]) + eps
// One wave = 16-row strip. 16x16x32 bf16 MFMA against PT (bf16, LDS).
// ---------------------------------------------------------------------------
template<int MODE>
__global__ __launch_bounds__(256) void featmap(
    const float* __restrict__ x, const float* __restrict__ proj,
    u16* __restrict__ outp, float* __restrict__ headmax)
{
    __shared__ u16 PT[64][72];      // PT[m][d] = bf16(proj[d][m]); stride 72 -> 2-way only
    __shared__ float ssrow[4][16];  // per-wave row sum-of-squares

    const int tid  = threadIdx.x;
    const int lane = tid & 63, wave = tid >> 6;
    const int l15  = lane & 15, lhi = lane >> 4;

    // stage PT (transpose proj), coalesced fp32 loads
    #pragma unroll
    for (int p = 0; p < 4; ++p) {
        int d = p * 16 + (tid >> 4);
        int m = (tid & 15) * 4;
        float4 pv = *(const float4*)(proj + d * 64 + m);
        PT[m + 0][d] = f2bf(pv.x);
        PT[m + 1][d] = f2bf(pv.y);
        PT[m + 2][d] = f2bf(pv.z);
        PT[m + 3][d] = f2bf(pv.w);
    }
    __syncthreads();

    const int strip = blockIdx.x * 4 + wave;   // 4096 strips x 16 rows = 65536 rows
    const int row0  = strip * 16;

    // A-fragments: lane covers row l15, k = d = {lhi*8..+8} and {32+lhi*8..+8}
    const float* xs = x + (size_t)(row0 + l15) * 64 + lhi * 8;
    float4 f0 = *(const float4*)(xs);
    float4 f1 = *(const float4*)(xs + 4);
    float4 f2 = *(const float4*)(xs + 32);
    float4 f3 = *(const float4*)(xs + 36);

    short8 a0, a1;
    a0[0] = (short)f2bf(f0.x); a0[1] = (short)f2bf(f0.y);
    a0[2] = (short)f2bf(f0.z); a0[3] = (short)f2bf(f0.w);
    a0[4] = (short)f2bf(f1.x); a0[5] = (short)f2bf(f1.y);
    a0[6] = (short)f2bf(f1.z); a0[7] = (short)f2bf(f1.w);
    a1[0] = (short)f2bf(f2.x); a1[1] = (short)f2bf(f2.y);
    a1[2] = (short)f2bf(f2.z); a1[3] = (short)f2bf(f2.w);
    a1[4] = (short)f2bf(f3.x); a1[5] = (short)f2bf(f3.y);
    a1[6] = (short)f2bf(f3.z); a1[7] = (short)f2bf(f3.w);

    // sum of squares for diag (exact fp32 inputs)
    float ss = f0.x*f0.x + f0.y*f0.y + f0.z*f0.z + f0.w*f0.w
             + f1.x*f1.x + f1.y*f1.y + f1.z*f1.z + f1.w*f1.w
             + f2.x*f2.x + f2.y*f2.y + f2.z*f2.z + f2.w*f2.w
             + f3.x*f3.x + f3.y*f3.y + f3.z*f3.z + f3.w*f3.w;
    ss += __shfl_xor(ss, 16);
    ss += __shfl_xor(ss, 32);
    if (MODE != 1) { if (lhi == 0) ssrow[wave][l15] = ss; }

    f32x4 c[4] = { {0,0,0,0}, {0,0,0,0}, {0,0,0,0}, {0,0,0,0} };
    #pragma unroll
    for (int ct = 0; ct < 4; ++ct) {
        short8 b0 = *(const short8*)&PT[ct * 16 + l15][lhi * 8];
        short8 b1 = *(const short8*)&PT[ct * 16 + l15][32 + lhi * 8];
        c[ct] = __builtin_amdgcn_mfma_f32_16x16x32_bf16(a0, b0, c[ct], 0, 0, 0);
        c[ct] = __builtin_amdgcn_mfma_f32_16x16x32_bf16(a1, b1, c[ct], 0, 0, 0);
    }

    // per-row max over m (NRM>0 so scale at the end commutes with max)
    float mx[4];
    #pragma unroll
    for (int r = 0; r < 4; ++r)
        mx[r] = fmaxf(fmaxf(c[0][r], c[1][r]), fmaxf(c[2][r], c[3][r]));
    #pragma unroll
    for (int r = 0; r < 4; ++r) {
        float m = mx[r];
        m = fmaxf(m, __shfl_xor(m, 1));
        m = fmaxf(m, __shfl_xor(m, 2));
        m = fmaxf(m, __shfl_xor(m, 4));
        m = fmaxf(m, __shfl_xor(m, 8));
        mx[r] = m;
    }

    if (MODE == 1) {
        float m2 = fmaxf(fmaxf(mx[0], mx[1]), fmaxf(mx[2], mx[3]));
        m2 = fmaxf(m2, __shfl_xor(m2, 16));
        m2 = fmaxf(m2, __shfl_xor(m2, 32));
        if (lane == 0) atomicMaxF(&headmax[row0 >> 10], m2 * NRM);
        return;
    }

    float stab = 0.f;
    if (MODE == 2) stab = headmax[row0 >> 10];

    asm volatile("s_waitcnt lgkmcnt(0)" ::: "memory");   // ssrow visible (intra-wave)
    float diag[4];
    #pragma unroll
    for (int r = 0; r < 4; ++r) diag[r] = ssrow[wave][lhi * 4 + r] * 0.0625f; // 0.5*NRM^2

    u16* op = outp + (size_t)row0 * 64;
    #pragma unroll
    for (int ct = 0; ct < 4; ++ct) {
        #pragma unroll
        for (int r = 0; r < 4; ++r) {
            float dd = c[ct][r] * NRM;
            float st = (MODE == 0) ? mx[r] * NRM : stab;
            float val = __expf(dd - diag[r] - st) + EPSF;
            op[(lhi * 4 + r) * 64 + ct * 16 + l15] = f2bf(val);
        }
    }
}

// ---------------------------------------------------------------------------
// v [bh][s][d] fp32  ->  vT [bh][d][s] bf16  (64x64 LDS tile transpose)
// ---------------------------------------------------------------------------
__global__ __launch_bounds__(256) void vtrans(const float* __restrict__ v,
                                              u16* __restrict__ vT)
{
    __shared__ u16 tile[64][72];
    const int tid = threadIdx.x;
    const int bh = blockIdx.x >> 4, s0 = (blockIdx.x & 15) << 6;
    const float* src = v + ((size_t)bh * 1024 + s0) * 64;
    #pragma unroll
    for (int p = 0; p < 4; ++p) {
        int s = p * 16 + (tid >> 4);
        int d = (tid & 15) * 4;
        float4 val = *(const float4*)(src + s * 64 + d);
        tile[d + 0][s] = f2bf(val.x);
        tile[d + 1][s] = f2bf(val.y);
        tile[d + 2][s] = f2bf(val.z);
        tile[d + 3][s] = f2bf(val.w);
    }
    __syncthreads();
    u16* dst = vT + (size_t)bh * 64 * 1024 + s0;
    #pragma unroll
    for (int p = 0; p < 4; ++p) {
        int d = p * 16 + (tid >> 4);
        int s = (tid & 15) * 4;
        ushort4 o;
        o.x = tile[d][s]; o.y = tile[d][s + 1];
        o.z = tile[d][s + 2]; o.w = tile[d][s + 3];
        *(ushort4*)(dst + d * 1024 + s) = o;
    }
}

// ---------------------------------------------------------------------------
// Causal flash: block = (head, 64-row q-tile), 4 waves x 16 rows.
// scores = qp @ kp^T (NT, both K-contiguous); mask diag tile; den in C-layout;
// scores -> per-wave LDS -> PV A-frags; PV B-frags straight from global vT.
// ---------------------------------------------------------------------------
__global__ __launch_bounds__(256) void attn(
    const u16* __restrict__ qp, const u16* __restrict__ kp,
    const u16* __restrict__ vT, float* __restrict__ out)
{
    __shared__ float sc[4][16][76];   // stride 76: 16B-aligned rows, 2-way conflicts only
    const int tid  = threadIdx.x;
    const int lane = tid & 63, wave = tid >> 6;
    const int l15  = lane & 15, lhi = lane >> 4;
    const int bh = blockIdx.x & 63;
    const int qi = 15 - (blockIdx.x >> 6);   // heavy q-tiles first

    const u16* qpb = qp + ((size_t)bh * 1024 + qi * 64 + wave * 16 + l15) * 64;
    const u16* kpb = kp + (size_t)bh * 1024 * 64;
    const u16* vTb = vT + (size_t)bh * 64 * 1024;

    short8 aq0 = *(const short8*)(qpb + lhi * 8);
    short8 aq1 = *(const short8*)(qpb + 32 + lhi * 8);

    f32x4 accn[4] = { {0,0,0,0}, {0,0,0,0}, {0,0,0,0}, {0,0,0,0} };
    float denp[4] = {0.f, 0.f, 0.f, 0.f};

    for (int kt = 0; kt <= qi; ++kt) {
        const u16* kpt = kpb + (size_t)kt * 64 * 64;
        // ---- scores: 16 rows x 64 cols per wave
        f32x4 s[4];
        #pragma unroll
        for (int ct = 0; ct < 4; ++ct) {
            const u16* kr = kpt + (ct * 16 + l15) * 64 + lhi * 8;
            short8 b0 = *(const short8*)(kr);
            short8 b1 = *(const short8*)(kr + 32);
            f32x4 acc = {0, 0, 0, 0};
            acc = __builtin_amdgcn_mfma_f32_16x16x32_bf16(aq0, b0, acc, 0, 0, 0);
            acc = __builtin_amdgcn_mfma_f32_16x16x32_bf16(aq1, b1, acc, 0, 0, 0);
            s[ct] = acc;
        }
        // ---- mask (diag tile), den accum, stash to LDS (C-layout -> [row][col])
        const int qrow = wave * 16 + lhi * 4;
        #pragma unroll
        for (int ct = 0; ct < 4; ++ct) {
            int tcol = ct * 16 + l15;
            #pragma unroll
            for (int r = 0; r < 4; ++r) {
                float vv = s[ct][r];
                if (kt == qi && tcol > qrow + r) vv = 0.f;
                denp[r] += vv;
                sc[wave][lhi * 4 + r][tcol] = vv;
            }
        }
        asm volatile("s_waitcnt lgkmcnt(0)" ::: "memory");  // intra-wave RAW on sc
        // ---- PV: A = scores (row=l15, k=t), B = vT (col=l15, k=t)
        #pragma unroll
        for (int kk = 0; kk < 2; ++kk) {
            const float* sr = &sc[wave][l15][kk * 32 + lhi * 8];
            float4 p0 = *(const float4*)(sr);
            float4 p1 = *(const float4*)(sr + 4);
            short8 ap;
            ap[0] = (short)f2bf(p0.x); ap[1] = (short)f2bf(p0.y);
            ap[2] = (short)f2bf(p0.z); ap[3] = (short)f2bf(p0.w);
            ap[4] = (short)f2bf(p1.x); ap[5] = (short)f2bf(p1.y);
            ap[6] = (short)f2bf(p1.z); ap[7] = (short)f2bf(p1.w);
            const u16* vr = vTb + kt * 64 + kk * 32 + lhi * 8;
            #pragma unroll
            for (int dt = 0; dt < 4; ++dt) {
                short8 bv = *(const short8*)(vr + (size_t)(dt * 16 + l15) * 1024);
                accn[dt] = __builtin_amdgcn_mfma_f32_16x16x32_bf16(ap, bv, accn[dt], 0, 0, 0);
            }
        }
    }

    // den: reduce over the 16 columns held across l15
    #pragma unroll
    for (int r = 0; r < 4; ++r) {
        float d = denp[r];
        d += __shfl_xor(d, 1);
        d += __shfl_xor(d, 2);
        d += __shfl_xor(d, 4);
        d += __shfl_xor(d, 8);
        denp[r] = d;
    }

    float* ob = out + ((size_t)bh * 1024 + qi * 64 + wave * 16) * 64;
    #pragma unroll
    for (int dt = 0; dt < 4; ++dt) {
        #pragma unroll
        for (int r = 0; r < 4; ++r) {
            ob[(lhi * 4 + r) * 64 + dt * 16 + l15] = accn[dt][r] / denp[r];
        }
    }
}

// ---------------------------------------------------------------------------
extern "C" void kernel_launch(void* const* d_in, const int* in_sizes, int n_in,
                              void* d_out, int out_size, void* d_ws, size_t ws_size,
                              hipStream_t stream)
{
    const float* q    = (const float*)d_in[0];
    const float* k    = (const float*)d_in[1];
    const float* v    = (const float*)d_in[2];
    const float* proj = (const float*)d_in[3];
    float* out = (float*)d_out;

    char* ws = (char*)d_ws;
    u16*  qpw = (u16*)(ws);                                  // 8 MB
    u16*  kpw = (u16*)(ws + (size_t)8 * 1024 * 1024);        // 8 MB
    u16*  vTw = (u16*)(ws + (size_t)16 * 1024 * 1024);       // 8 MB
    float* hm = (float*)(ws + (size_t)24 * 1024 * 1024);     // 256 B

    hipLaunchKernelGGL(init_hm, dim3(1), dim3(64), 0, stream, hm);
    hipLaunchKernelGGL((featmap<0>), dim3(1024), dim3(256), 0, stream, q, proj, qpw, (float*)nullptr);
    hipLaunchKernelGGL((featmap<1>), dim3(1024), dim3(256), 0, stream, k, proj, (u16*)nullptr, hm);
    hipLaunchKernelGGL((featmap<2>), dim3(1024), dim3(256), 0, stream, k, proj, kpw, hm);
    hipLaunchKernelGGL(vtrans, dim3(1024), dim3(256), 0, stream, v, vTw);
    hipLaunchKernelGGL(attn, dim3(1024), dim3(256), 0, stream, qpw, kpw, vTw, out);
}

// Round 2
// 116.236 us; speedup vs baseline: 1.1263x; 1.1263x over previous
//
#include <hip/hip_runtime.h>
#include <hip/hip_bf16.h>

// Performer FAVOR+ causal attention, MI355X gfx950.
// B=4 H=16 S=1024 D=64 M=64. fp32 in/out, bf16 MFMA internally.
// R2: attn with zero-LDS swapped-QK^T score path + register prefetch.

#define NRM 0.35355339059327373f   // 64^-0.25
#define EPSF 1e-4f

typedef __attribute__((ext_vector_type(8))) short short8;
typedef __attribute__((ext_vector_type(4))) float f32x4;
typedef __attribute__((ext_vector_type(4))) unsigned uint4v;
typedef unsigned short u16;

__device__ inline u16 f2bf(float f) {
    unsigned u = __float_as_uint(f);
    return (u16)((u + 0x7FFFu + ((u >> 16) & 1u)) >> 16);   // RNE
}
__device__ inline float bf2f(u16 h) { return __uint_as_float(((unsigned)h) << 16); }
__device__ inline unsigned cvtpk(float lo, float hi) {
    unsigned r; asm("v_cvt_pk_bf16_f32 %0, %1, %2" : "=v"(r) : "v"(lo), "v"(hi)); return r;
}
__device__ inline void atomicMaxF(float* a, float v) {
    if (v >= 0.f) atomicMax((int*)a, __float_as_int(v));
    else          atomicMin((unsigned int*)a, (unsigned int)__float_as_int(v));
}

__global__ void init_hm(float* hm) { hm[threadIdx.x] = -INFINITY; }

// ---------------------------------------------------------------------------
// prep: blocks 0..1023 q-featmap -> qp; 1024..2047 k-featmap -> dd(bf16,scaled),
// diag, head-max; 2048..3071 v transpose -> vT.
// ---------------------------------------------------------------------------
__global__ __launch_bounds__(256) void prep(
    const float* __restrict__ q, const float* __restrict__ k,
    const float* __restrict__ v, const float* __restrict__ proj,
    u16* __restrict__ qp, u16* __restrict__ ddkp,
    float* __restrict__ dsw, float* __restrict__ hm, u16* __restrict__ vT)
{
    __shared__ u16 PT[64][72];
    __shared__ u16 tile[64][72];
    const int tid = threadIdx.x, lane = tid & 63, wave = tid >> 6;
    const int l15 = lane & 15, lhi = lane >> 4;
    const int bid = blockIdx.x;

    if (bid >= 2048) {   // ---- v transpose
        const int b2 = bid - 2048;
        const int bh = b2 >> 4, s0 = (b2 & 15) << 6;
        const float* src = v + ((size_t)bh * 1024 + s0) * 64;
        #pragma unroll
        for (int p = 0; p < 4; ++p) {
            int s = p * 16 + (tid >> 4);
            int d = (tid & 15) * 4;
            float4 val = *(const float4*)(src + s * 64 + d);
            tile[d + 0][s] = f2bf(val.x);
            tile[d + 1][s] = f2bf(val.y);
            tile[d + 2][s] = f2bf(val.z);
            tile[d + 3][s] = f2bf(val.w);
        }
        __syncthreads();
        u16* dst = vT + (size_t)bh * 65536 + s0;
        #pragma unroll
        for (int p = 0; p < 4; ++p) {
            int d = p * 16 + (tid >> 4);
            int s = (tid & 15) * 4;
            ushort4 o;
            o.x = tile[d][s]; o.y = tile[d][s + 1];
            o.z = tile[d][s + 2]; o.w = tile[d][s + 3];
            *(ushort4*)(dst + d * 1024 + s) = o;
        }
        return;
    }

    // ---- feature map (q or k)
    const bool isQ = bid < 1024;
    const float* x = isQ ? q : k;

    #pragma unroll
    for (int p = 0; p < 4; ++p) {
        int d = p * 16 + (tid >> 4);
        int m = (tid & 15) * 4;
        float4 pv = *(const float4*)(proj + d * 64 + m);
        PT[m + 0][d] = f2bf(pv.x);
        PT[m + 1][d] = f2bf(pv.y);
        PT[m + 2][d] = f2bf(pv.z);
        PT[m + 3][d] = f2bf(pv.w);
    }
    __syncthreads();

    const int strip = (bid & 1023) * 4 + wave;   // 0..4095
    const int row0  = strip * 16;

    const float* xs = x + (size_t)(row0 + l15) * 64 + lhi * 8;
    float4 f0 = *(const float4*)(xs);
    float4 f1 = *(const float4*)(xs + 4);
    float4 f2 = *(const float4*)(xs + 32);
    float4 f3 = *(const float4*)(xs + 36);

    short8 a0, a1;
    a0[0] = (short)f2bf(f0.x); a0[1] = (short)f2bf(f0.y);
    a0[2] = (short)f2bf(f0.z); a0[3] = (short)f2bf(f0.w);
    a0[4] = (short)f2bf(f1.x); a0[5] = (short)f2bf(f1.y);
    a0[6] = (short)f2bf(f1.z); a0[7] = (short)f2bf(f1.w);
    a1[0] = (short)f2bf(f2.x); a1[1] = (short)f2bf(f2.y);
    a1[2] = (short)f2bf(f2.z); a1[3] = (short)f2bf(f2.w);
    a1[4] = (short)f2bf(f3.x); a1[5] = (short)f2bf(f3.y);
    a1[6] = (short)f2bf(f3.z); a1[7] = (short)f2bf(f3.w);

    float ss = f0.x*f0.x + f0.y*f0.y + f0.z*f0.z + f0.w*f0.w
             + f1.x*f1.x + f1.y*f1.y + f1.z*f1.z + f1.w*f1.w
             + f2.x*f2.x + f2.y*f2.y + f2.z*f2.z + f2.w*f2.w
             + f3.x*f3.x + f3.y*f3.y + f3.z*f3.z + f3.w*f3.w;
    ss += __shfl_xor(ss, 16);
    ss += __shfl_xor(ss, 32);          // full row sum-of-squares at every lane

    f32x4 c[4] = { {0,0,0,0}, {0,0,0,0}, {0,0,0,0}, {0,0,0,0} };
    #pragma unroll
    for (int ct = 0; ct < 4; ++ct) {
        short8 b0 = *(const short8*)&PT[ct * 16 + l15][lhi * 8];
        short8 b1 = *(const short8*)&PT[ct * 16 + l15][32 + lhi * 8];
        c[ct] = __builtin_amdgcn_mfma_f32_16x16x32_bf16(a0, b0, c[ct], 0, 0, 0);
        c[ct] = __builtin_amdgcn_mfma_f32_16x16x32_bf16(a1, b1, c[ct], 0, 0, 0);
    }

    float mx[4];
    #pragma unroll
    for (int r = 0; r < 4; ++r)
        mx[r] = fmaxf(fmaxf(c[0][r], c[1][r]), fmaxf(c[2][r], c[3][r]));
    #pragma unroll
    for (int r = 0; r < 4; ++r) {
        float m = mx[r];
        m = fmaxf(m, __shfl_xor(m, 1));
        m = fmaxf(m, __shfl_xor(m, 2));
        m = fmaxf(m, __shfl_xor(m, 4));
        m = fmaxf(m, __shfl_xor(m, 8));
        mx[r] = m;
    }

    if (isQ) {
        float diag[4];
        #pragma unroll
        for (int r = 0; r < 4; ++r) diag[r] = __shfl(ss, lhi * 4 + r) * 0.0625f;
        u16* op = qp + (size_t)row0 * 64;
        #pragma unroll
        for (int ct = 0; ct < 4; ++ct) {
            #pragma unroll
            for (int r = 0; r < 4; ++r) {
                float val = __expf(c[ct][r] * NRM - diag[r] - mx[r] * NRM) + EPSF;
                op[(lhi * 4 + r) * 64 + ct * 16 + l15] = f2bf(val);
            }
        }
    } else {
        float m2 = fmaxf(fmaxf(mx[0], mx[1]), fmaxf(mx[2], mx[3]));
        m2 = fmaxf(m2, __shfl_xor(m2, 16));
        m2 = fmaxf(m2, __shfl_xor(m2, 32));
        if (lane == 0) atomicMaxF(&hm[strip >> 6], m2 * NRM);
        if (lhi == 0) dsw[row0 + l15] = ss * 0.0625f;
        u16* op = ddkp + (size_t)row0 * 64;
        #pragma unroll
        for (int ct = 0; ct < 4; ++ct) {
            #pragma unroll
            for (int r = 0; r < 4; ++r)
                op[(lhi * 4 + r) * 64 + ct * 16 + l15] = f2bf(c[ct][r] * NRM);
        }
    }
}

// ---------------------------------------------------------------------------
// kp finish: kp = exp(dd_scaled - diag - headmax) + eps   (in place, bf16)
// ---------------------------------------------------------------------------
__global__ __launch_bounds__(256) void kpfin(u16* __restrict__ kp,
    const float* __restrict__ dsw, const float* __restrict__ hm)
{
    const int gid = blockIdx.x * 256 + threadIdx.x;   // 0..262143
    const int row = gid >> 2;
    const int off = (gid & 3) * 16;
    const float sub = dsw[row] + hm[row >> 10];
    u16* p = kp + (size_t)row * 64 + off;
    short8 d0 = *(const short8*)(p);
    short8 d1 = *(const short8*)(p + 8);
    short8 o0, o1;
    #pragma unroll
    for (int j = 0; j < 8; ++j) {
        o0[j] = (short)f2bf(__expf(bf2f((u16)d0[j]) - sub) + EPSF);
        o1[j] = (short)f2bf(__expf(bf2f((u16)d1[j]) - sub) + EPSF);
    }
    *(short8*)(p)     = o0;
    *(short8*)(p + 8) = o1;
}

// ---------------------------------------------------------------------------
// attn: block = (bh, q-tile t). 4 waves x 16 q-rows, kt = 0..t.
// S^T = mfma(kp_perm, qp): lane holds q-row l15, k-slots land directly in the
// PV A-fragment positions (k = 8*lhi + j + 32*kk) -> zero-shuffle cvt_pk.
// kp double-buffered in registers; vT issued early each iteration. No LDS.
// ---------------------------------------------------------------------------
struct KF { short8 f[8]; };

__global__ __launch_bounds__(256) void attn(
    const u16* __restrict__ qp, const u16* __restrict__ kp,
    const u16* __restrict__ vT, float* __restrict__ out)
{
    const int tid = threadIdx.x, lane = tid & 63, wave = tid >> 6;
    const int l15 = lane & 15, lhi = lane >> 4;
    const int bh = blockIdx.x & 63;
    const int t  = 15 - (blockIdx.x >> 6);   // heavy q-tiles dispatched first

    const u16* qpr = qp + ((size_t)bh * 1024 + t * 64 + wave * 16 + l15) * 64 + lhi * 8;
    short8 aq0 = *(const short8*)(qpr);
    short8 aq1 = *(const short8*)(qpr + 32);

    // permuted K-row base: f(ct,l15) = 8*(l15>>2)+(l15&3) + {0,4,32,36}[ct]
    const u16* kpb = kp + (size_t)bh * 65536 + (size_t)(8 * (l15 >> 2) + (l15 & 3)) * 64 + lhi * 8;
    const u16* vTb = vT + (size_t)bh * 65536 + (size_t)l15 * 1024 + lhi * 8;

    f32x4 acc0 = {0,0,0,0}, acc1 = {0,0,0,0}, acc2 = {0,0,0,0}, acc3 = {0,0,0,0};
    float den = 0.f;

    auto loadK = [&](int kt, KF& kf) {
        const u16* b = kpb + (size_t)kt * 4096;
        kf.f[0] = *(const short8*)(b);
        kf.f[1] = *(const short8*)(b + 32);
        kf.f[2] = *(const short8*)(b + 256);    // row +4
        kf.f[3] = *(const short8*)(b + 288);
        kf.f[4] = *(const short8*)(b + 2048);   // row +32
        kf.f[5] = *(const short8*)(b + 2080);
        kf.f[6] = *(const short8*)(b + 2304);   // row +36
        kf.f[7] = *(const short8*)(b + 2336);
    };

    auto body = [&](int kt, const KF& kf) {
        const u16* vb = vTb + (size_t)kt * 64;
        short8 v0 = *(const short8*)(vb);
        short8 v1 = *(const short8*)(vb + 32);
        short8 v2 = *(const short8*)(vb + 16384);
        short8 v3 = *(const short8*)(vb + 16384 + 32);
        short8 v4 = *(const short8*)(vb + 32768);
        short8 v5 = *(const short8*)(vb + 32768 + 32);
        short8 v6 = *(const short8*)(vb + 49152);
        short8 v7 = *(const short8*)(vb + 49152 + 32);

        f32x4 s0 = {0,0,0,0}, s1 = {0,0,0,0}, s2 = {0,0,0,0}, s3 = {0,0,0,0};
        __builtin_amdgcn_s_setprio(1);
        s0 = __builtin_amdgcn_mfma_f32_16x16x32_bf16(kf.f[0], aq0, s0, 0, 0, 0);
        s0 = __builtin_amdgcn_mfma_f32_16x16x32_bf16(kf.f[1], aq1, s0, 0, 0, 0);
        s1 = __builtin_amdgcn_mfma_f32_16x16x32_bf16(kf.f[2], aq0, s1, 0, 0, 0);
        s1 = __builtin_amdgcn_mfma_f32_16x16x32_bf16(kf.f[3], aq1, s1, 0, 0, 0);
        s2 = __builtin_amdgcn_mfma_f32_16x16x32_bf16(kf.f[4], aq0, s2, 0, 0, 0);
        s2 = __builtin_amdgcn_mfma_f32_16x16x32_bf16(kf.f[5], aq1, s2, 0, 0, 0);
        s3 = __builtin_amdgcn_mfma_f32_16x16x32_bf16(kf.f[6], aq0, s3, 0, 0, 0);
        s3 = __builtin_amdgcn_mfma_f32_16x16x32_bf16(kf.f[7], aq1, s3, 0, 0, 0);
        __builtin_amdgcn_s_setprio(0);

        if (kt == t) {   // diagonal tile causal mask (within-tile indices)
            const int qr = wave * 16 + l15;
            const int kc = 8 * lhi;
            #pragma unroll
            for (int r = 0; r < 4; ++r) {
                if (kc + r      > qr) s0[r] = 0.f;
                if (kc + 4 + r  > qr) s1[r] = 0.f;
                if (kc + 32 + r > qr) s2[r] = 0.f;
                if (kc + 36 + r > qr) s3[r] = 0.f;
            }
        }
        float t0 = (s0[0] + s0[1]) + (s0[2] + s0[3]);
        float t1 = (s1[0] + s1[1]) + (s1[2] + s1[3]);
        float t2 = (s2[0] + s2[1]) + (s2[2] + s2[3]);
        float t3 = (s3[0] + s3[1]) + (s3[2] + s3[3]);
        den += (t0 + t1) + (t2 + t3);

        uint4v w0 = { cvtpk(s0[0], s0[1]), cvtpk(s0[2], s0[3]),
                      cvtpk(s1[0], s1[1]), cvtpk(s1[2], s1[3]) };
        uint4v w1 = { cvtpk(s2[0], s2[1]), cvtpk(s2[2], s2[3]),
                      cvtpk(s3[0], s3[1]), cvtpk(s3[2], s3[3]) };
        short8 pa0 = __builtin_bit_cast(short8, w0);
        short8 pa1 = __builtin_bit_cast(short8, w1);

        __builtin_amdgcn_s_setprio(1);
        acc0 = __builtin_amdgcn_mfma_f32_16x16x32_bf16(pa0, v0, acc0, 0, 0, 0);
        acc0 = __builtin_amdgcn_mfma_f32_16x16x32_bf16(pa1, v1, acc0, 0, 0, 0);
        acc1 = __builtin_amdgcn_mfma_f32_16x16x32_bf16(pa0, v2, acc1, 0, 0, 0);
        acc1 = __builtin_amdgcn_mfma_f32_16x16x32_bf16(pa1, v3, acc1, 0, 0, 0);
        acc2 = __builtin_amdgcn_mfma_f32_16x16x32_bf16(pa0, v4, acc2, 0, 0, 0);
        acc2 = __builtin_amdgcn_mfma_f32_16x16x32_bf16(pa1, v5, acc2, 0, 0, 0);
        acc3 = __builtin_amdgcn_mfma_f32_16x16x32_bf16(pa0, v6, acc3, 0, 0, 0);
        acc3 = __builtin_amdgcn_mfma_f32_16x16x32_bf16(pa1, v7, acc3, 0, 0, 0);
        __builtin_amdgcn_s_setprio(0);
    };

    KF kA, kB;
    loadK(0, kA);
    int kt = 0;
    for (;;) {
        if (kt < t) loadK(kt + 1, kB);
        body(kt, kA);
        if (kt >= t) break;
        ++kt;
        if (kt < t) loadK(kt + 1, kA);
        body(kt, kB);
        if (kt >= t) break;
        ++kt;
    }

    den += __shfl_xor(den, 16);
    den += __shfl_xor(den, 32);
    float inv[4];
    #pragma unroll
    for (int r = 0; r < 4; ++r) inv[r] = 1.0f / __shfl(den, lhi * 4 + r);

    float* ob = out + ((size_t)bh * 1024 + t * 64 + wave * 16) * 64;
    #pragma unroll
    for (int r = 0; r < 4; ++r) {
        ob[(lhi * 4 + r) * 64 +  0 + l15] = acc0[r] * inv[r];
        ob[(lhi * 4 + r) * 64 + 16 + l15] = acc1[r] * inv[r];
        ob[(lhi * 4 + r) * 64 + 32 + l15] = acc2[r] * inv[r];
        ob[(lhi * 4 + r) * 64 + 48 + l15] = acc3[r] * inv[r];
    }
}

// ---------------------------------------------------------------------------
extern "C" void kernel_launch(void* const* d_in, const int* in_sizes, int n_in,
                              void* d_out, int out_size, void* d_ws, size_t ws_size,
                              hipStream_t stream)
{
    const float* q    = (const float*)d_in[0];
    const float* k    = (const float*)d_in[1];
    const float* v    = (const float*)d_in[2];
    const float* proj = (const float*)d_in[3];
    float* out = (float*)d_out;

    char* ws = (char*)d_ws;
    u16*   qpw = (u16*)(ws);                                   // 8 MB
    u16*   kpw = (u16*)(ws + (size_t)8 * 1024 * 1024);         // 8 MB (dd then kp)
    u16*   vTw = (u16*)(ws + (size_t)16 * 1024 * 1024);        // 8 MB
    float* hm  = (float*)(ws + (size_t)24 * 1024 * 1024);      // 256 B
    float* dsw = (float*)(ws + (size_t)24 * 1024 * 1024 + 4096); // 256 KB

    hipLaunchKernelGGL(init_hm, dim3(1), dim3(64), 0, stream, hm);
    hipLaunchKernelGGL(prep, dim3(3072), dim3(256), 0, stream,
                       q, k, v, proj, qpw, kpw, dsw, hm, vTw);
    hipLaunchKernelGGL(kpfin, dim3(1024), dim3(256), 0, stream, kpw, dsw, hm);
    hipLaunchKernelGGL(attn, dim3(1024), dim3(256), 0, stream, qpw, kpw, vTw, out);
}

// Round 3
// 36.510 us; speedup vs baseline: 3.5858x; 3.1837x over previous
//
#include <hip/hip_runtime.h>
#include <hip/hip_bf16.h>

// Performer FAVOR+ causal attention, MI355X gfx950.
// B=4 H=16 S=1024 D=64 M=64. fp32 in/out, bf16 MFMA internally.
// R3: LDS-staged 2-phase pipelined attn, strip-paired uniform work, no k-stab.

#define NRM 0.35355339059327373f   // 64^-0.25
#define EPSF 1e-4f

typedef __attribute__((ext_vector_type(8))) short short8;
typedef __attribute__((ext_vector_type(4))) float f32x4;
typedef __attribute__((ext_vector_type(4))) unsigned uint4v;
typedef unsigned short u16;

__device__ inline u16 f2bf(float f) {
    unsigned u = __float_as_uint(f);
    return (u16)((u + 0x7FFFu + ((u >> 16) & 1u)) >> 16);   // RNE
}
__device__ inline unsigned cvtpk(float lo, float hi) {
    unsigned r; asm("v_cvt_pk_bf16_f32 %0, %1, %2" : "=v"(r) : "v"(lo), "v"(hi)); return r;
}

// ---------------------------------------------------------------------------
// prep: blocks 0..1023 q-featmap -> qp (per-row stab);
//       1024..2047 k-featmap -> kp = exp(dd - diag) + eps (stab dropped: a
//       per-head constant factor cancels in row-normalization up to O(eps));
//       2048..3071 v transpose -> vT [bh][d][s] bf16.
// ---------------------------------------------------------------------------
__global__ __launch_bounds__(256) void prep(
    const float* __restrict__ q, const float* __restrict__ k,
    const float* __restrict__ v, const float* __restrict__ proj,
    u16* __restrict__ qp, u16* __restrict__ kp, u16* __restrict__ vT)
{
    __shared__ u16 PT[64][72];
    __shared__ u16 tile[64][72];
    const int tid = threadIdx.x, lane = tid & 63, wave = tid >> 6;
    const int l15 = lane & 15, lhi = lane >> 4;
    const int bid = blockIdx.x;

    if (bid >= 2048) {   // ---- v transpose
        const int b2 = bid - 2048;
        const int bh = b2 >> 4, s0 = (b2 & 15) << 6;
        const float* src = v + ((size_t)bh * 1024 + s0) * 64;
        #pragma unroll
        for (int p = 0; p < 4; ++p) {
            int s = p * 16 + (tid >> 4);
            int d = (tid & 15) * 4;
            float4 val = *(const float4*)(src + s * 64 + d);
            tile[d + 0][s] = f2bf(val.x);
            tile[d + 1][s] = f2bf(val.y);
            tile[d + 2][s] = f2bf(val.z);
            tile[d + 3][s] = f2bf(val.w);
        }
        __syncthreads();
        u16* dst = vT + (size_t)bh * 65536 + s0;
        #pragma unroll
        for (int p = 0; p < 4; ++p) {
            int d = p * 16 + (tid >> 4);
            int s = (tid & 15) * 4;
            ushort4 o;
            o.x = tile[d][s]; o.y = tile[d][s + 1];
            o.z = tile[d][s + 2]; o.w = tile[d][s + 3];
            *(ushort4*)(dst + d * 1024 + s) = o;
        }
        return;
    }

    const bool isQ = bid < 1024;
    const float* x = isQ ? q : k;

    #pragma unroll
    for (int p = 0; p < 4; ++p) {
        int d = p * 16 + (tid >> 4);
        int m = (tid & 15) * 4;
        float4 pv = *(const float4*)(proj + d * 64 + m);
        PT[m + 0][d] = f2bf(pv.x);
        PT[m + 1][d] = f2bf(pv.y);
        PT[m + 2][d] = f2bf(pv.z);
        PT[m + 3][d] = f2bf(pv.w);
    }
    __syncthreads();

    const int strip = (bid & 1023) * 4 + wave;
    const int row0  = strip * 16;

    const float* xs = x + (size_t)(row0 + l15) * 64 + lhi * 8;
    float4 f0 = *(const float4*)(xs);
    float4 f1 = *(const float4*)(xs + 4);
    float4 f2 = *(const float4*)(xs + 32);
    float4 f3 = *(const float4*)(xs + 36);

    short8 a0, a1;
    a0[0] = (short)f2bf(f0.x); a0[1] = (short)f2bf(f0.y);
    a0[2] = (short)f2bf(f0.z); a0[3] = (short)f2bf(f0.w);
    a0[4] = (short)f2bf(f1.x); a0[5] = (short)f2bf(f1.y);
    a0[6] = (short)f2bf(f1.z); a0[7] = (short)f2bf(f1.w);
    a1[0] = (short)f2bf(f2.x); a1[1] = (short)f2bf(f2.y);
    a1[2] = (short)f2bf(f2.z); a1[3] = (short)f2bf(f2.w);
    a1[4] = (short)f2bf(f3.x); a1[5] = (short)f2bf(f3.y);
    a1[6] = (short)f2bf(f3.z); a1[7] = (short)f2bf(f3.w);

    float ss = f0.x*f0.x + f0.y*f0.y + f0.z*f0.z + f0.w*f0.w
             + f1.x*f1.x + f1.y*f1.y + f1.z*f1.z + f1.w*f1.w
             + f2.x*f2.x + f2.y*f2.y + f2.z*f2.z + f2.w*f2.w
             + f3.x*f3.x + f3.y*f3.y + f3.z*f3.z + f3.w*f3.w;
    ss += __shfl_xor(ss, 16);
    ss += __shfl_xor(ss, 32);

    f32x4 c[4] = { {0,0,0,0}, {0,0,0,0}, {0,0,0,0}, {0,0,0,0} };
    #pragma unroll
    for (int ct = 0; ct < 4; ++ct) {
        short8 b0 = *(const short8*)&PT[ct * 16 + l15][lhi * 8];
        short8 b1 = *(const short8*)&PT[ct * 16 + l15][32 + lhi * 8];
        c[ct] = __builtin_amdgcn_mfma_f32_16x16x32_bf16(a0, b0, c[ct], 0, 0, 0);
        c[ct] = __builtin_amdgcn_mfma_f32_16x16x32_bf16(a1, b1, c[ct], 0, 0, 0);
    }

    float diag[4];
    #pragma unroll
    for (int r = 0; r < 4; ++r) diag[r] = __shfl(ss, lhi * 4 + r) * 0.0625f; // 0.5*NRM^2

    if (isQ) {
        float mx[4];
        #pragma unroll
        for (int r = 0; r < 4; ++r)
            mx[r] = fmaxf(fmaxf(c[0][r], c[1][r]), fmaxf(c[2][r], c[3][r]));
        #pragma unroll
        for (int r = 0; r < 4; ++r) {
            float m = mx[r];
            m = fmaxf(m, __shfl_xor(m, 1));
            m = fmaxf(m, __shfl_xor(m, 2));
            m = fmaxf(m, __shfl_xor(m, 4));
            m = fmaxf(m, __shfl_xor(m, 8));
            mx[r] = m;
        }
        u16* op = qp + (size_t)row0 * 64;
        #pragma unroll
        for (int ct = 0; ct < 4; ++ct) {
            #pragma unroll
            for (int r = 0; r < 4; ++r) {
                float val = __expf(c[ct][r] * NRM - diag[r] - mx[r] * NRM) + EPSF;
                op[(lhi * 4 + r) * 64 + ct * 16 + l15] = f2bf(val);
            }
        }
    } else {
        u16* op = kp + (size_t)row0 * 64;
        #pragma unroll
        for (int ct = 0; ct < 4; ++ct) {
            #pragma unroll
            for (int r = 0; r < 4; ++r) {
                float val = __expf(c[ct][r] * NRM - diag[r]) + EPSF;
                op[(lhi * 4 + r) * 64 + ct * 16 + l15] = f2bf(val);
            }
        }
    }
}

// ---------------------------------------------------------------------------
// attn: 512 blocks x 256 thr. Block (h, j): wave w handles strips 4j+w and
// 63-(4j+w) -> 17 MFMA-rounds/wave uniform. K/V tiles double-buffered in LDS
// (XOR-swizzled), staged cooperatively; 2-phase pipeline, 1 barrier/round.
// ---------------------------------------------------------------------------
__global__ __launch_bounds__(256, 2) void attn(
    const u16* __restrict__ qp, const u16* __restrict__ kp,
    const u16* __restrict__ vT, float* __restrict__ out)
{
    __shared__ char lds[2][16384];   // [buf]: kp tile 8KB | vT tile 8KB

    const int tid = threadIdx.x, lane = tid & 63, wave = tid >> 6;
    const int l15 = lane & 15, lhi = lane >> 4;
    const int x = blockIdx.x;
    const int h = (((x >> 6) << 3)) | (x & 7);   // head: 8 blocks/head on one XCD
    const int j = (x >> 3) & 7;                  // 0..7

    const u16* kph = kp + (size_t)h * 65536;
    const u16* vTh = vT + (size_t)h * 65536;

    // ---- staging assignment: wave 0,1 -> kp chunks 0-3/4-7; wave 2,3 -> vT
    const int rch = lane >> 3;            // row within 8-row chunk
    const int cb  = (lane & 7) * 16;      // col byte within 128B row
    const bool isK = wave < 2;
    const int cbase = (wave & 1) * 4;
    const int gstride = isK ? 4096 : 64;  // elements per kt step

    int lo0, lo1, lo2, lo3;
    const u16 *go0, *go1, *go2, *go3;
    {
        #define STG(cc, LO, GO)                                                 \
        {   int i = cbase + cc; int row = 8 * i + rch;                          \
            int nib = (row & 3) | (((row >> 3) & 1) << 2);                      \
            LO = (isK ? 0 : 8192) + row * 128 + (cb ^ (nib << 4));              \
            GO = isK ? (kph + row * 64 + (cb >> 1))                             \
                     : (vTh + (size_t)row * 1024 + (cb >> 1)); }
        STG(0, lo0, go0) STG(1, lo1, go1) STG(2, lo2, go2) STG(3, lo3, go3)
        #undef STG
    }

    // ---- fragment-read offsets (bytes, swizzled)
    const int rowp = 8 * (l15 >> 2) + (l15 & 3);
    const int nk = (l15 & 3) | (((l15 >> 2) & 1) << 2);
    const int nv = (l15 & 3) | (((l15 >> 3) & 1) << 2);
    const int ok0 = rowp * 128 + ((16 * lhi) ^ (nk << 4));
    const int ok1 = rowp * 128 + ((64 + 16 * lhi) ^ (nk << 4));
    const int ov0 = 8192 + l15 * 128 + ((16 * lhi) ^ (nv << 4));
    const int ov1 = 8192 + l15 * 128 + ((64 + 16 * lhi) ^ (nv << 4));

    short8 ls0, ls1, ls2, ls3;   // staging registers

    auto stageLoad = [&](int kt) {
        ls0 = *(const short8*)(go0 + (size_t)kt * gstride);
        ls1 = *(const short8*)(go1 + (size_t)kt * gstride);
        ls2 = *(const short8*)(go2 + (size_t)kt * gstride);
        ls3 = *(const short8*)(go3 + (size_t)kt * gstride);
    };
    auto stageWrite = [&](char* B) {
        *(short8*)(B + lo0) = ls0;
        *(short8*)(B + lo1) = ls1;
        *(short8*)(B + lo2) = ls2;
        *(short8*)(B + lo3) = ls3;
    };

    auto runStrip = [&](int sigma, int T) {
        const u16* qpr = qp + ((size_t)h * 1024 + sigma * 16 + l15) * 64 + lhi * 8;
        short8 aq0 = *(const short8*)(qpr);
        short8 aq1 = *(const short8*)(qpr + 32);
        const int qrl = ((sigma & 3) << 4) + l15;   // local q-row in diag tile

        f32x4 acc0 = {0,0,0,0}, acc1 = {0,0,0,0}, acc2 = {0,0,0,0}, acc3 = {0,0,0,0};
        float den = 0.f;

        // prologue: stage tile 0 into buf 0
        stageLoad(0);
        stageWrite(lds[0]);
        __syncthreads();

        int cur = 0;
        for (int kt = 0; kt <= T; ++kt) {
            if (kt < T) stageLoad(kt + 1);

            const char* B = lds[cur];
            short8 k0 = *(const short8*)(B + ok0);
            short8 k1 = *(const short8*)(B + ok1);
            short8 k2 = *(const short8*)(B + ok0 + 512);
            short8 k3 = *(const short8*)(B + ok1 + 512);
            short8 k4 = *(const short8*)(B + ok0 + 4096);
            short8 k5 = *(const short8*)(B + ok1 + 4096);
            short8 k6 = *(const short8*)(B + ok0 + 4608);
            short8 k7 = *(const short8*)(B + ok1 + 4608);
            short8 v0 = *(const short8*)(B + ov0);
            short8 v1 = *(const short8*)(B + ov1);
            short8 v2 = *(const short8*)(B + ov0 + 2048);
            short8 v3 = *(const short8*)(B + ov1 + 2048);
            short8 v4 = *(const short8*)(B + ov0 + 4096);
            short8 v5 = *(const short8*)(B + ov1 + 4096);
            short8 v6 = *(const short8*)(B + ov0 + 6144);
            short8 v7 = *(const short8*)(B + ov1 + 6144);

            f32x4 s0 = {0,0,0,0}, s1 = {0,0,0,0}, s2 = {0,0,0,0}, s3 = {0,0,0,0};
            __builtin_amdgcn_s_setprio(1);
            s0 = __builtin_amdgcn_mfma_f32_16x16x32_bf16(k0, aq0, s0, 0, 0, 0);
            s0 = __builtin_amdgcn_mfma_f32_16x16x32_bf16(k1, aq1, s0, 0, 0, 0);
            s1 = __builtin_amdgcn_mfma_f32_16x16x32_bf16(k2, aq0, s1, 0, 0, 0);
            s1 = __builtin_amdgcn_mfma_f32_16x16x32_bf16(k3, aq1, s1, 0, 0, 0);
            s2 = __builtin_amdgcn_mfma_f32_16x16x32_bf16(k4, aq0, s2, 0, 0, 0);
            s2 = __builtin_amdgcn_mfma_f32_16x16x32_bf16(k5, aq1, s2, 0, 0, 0);
            s3 = __builtin_amdgcn_mfma_f32_16x16x32_bf16(k6, aq0, s3, 0, 0, 0);
            s3 = __builtin_amdgcn_mfma_f32_16x16x32_bf16(k7, aq1, s3, 0, 0, 0);
            __builtin_amdgcn_s_setprio(0);

            if (kt == T) {   // diagonal-tile causal mask
                const int kc = 8 * lhi;
                #pragma unroll
                for (int r = 0; r < 4; ++r) {
                    if (kc + r      > qrl) s0[r] = 0.f;
                    if (kc + 4 + r  > qrl) s1[r] = 0.f;
                    if (kc + 32 + r > qrl) s2[r] = 0.f;
                    if (kc + 36 + r > qrl) s3[r] = 0.f;
                }
            }
            float t0 = (s0[0] + s0[1]) + (s0[2] + s0[3]);
            float t1 = (s1[0] + s1[1]) + (s1[2] + s1[3]);
            float t2 = (s2[0] + s2[1]) + (s2[2] + s2[3]);
            float t3 = (s3[0] + s3[1]) + (s3[2] + s3[3]);
            den += (t0 + t1) + (t2 + t3);

            uint4v w0 = { cvtpk(s0[0], s0[1]), cvtpk(s0[2], s0[3]),
                          cvtpk(s1[0], s1[1]), cvtpk(s1[2], s1[3]) };
            uint4v w1 = { cvtpk(s2[0], s2[1]), cvtpk(s2[2], s2[3]),
                          cvtpk(s3[0], s3[1]), cvtpk(s3[2], s3[3]) };
            short8 pa0 = __builtin_bit_cast(short8, w0);
            short8 pa1 = __builtin_bit_cast(short8, w1);

            __builtin_amdgcn_s_setprio(1);
            acc0 = __builtin_amdgcn_mfma_f32_16x16x32_bf16(pa0, v0, acc0, 0, 0, 0);
            acc0 = __builtin_amdgcn_mfma_f32_16x16x32_bf16(pa1, v1, acc0, 0, 0, 0);
            acc1 = __builtin_amdgcn_mfma_f32_16x16x32_bf16(pa0, v2, acc1, 0, 0, 0);
            acc1 = __builtin_amdgcn_mfma_f32_16x16x32_bf16(pa1, v3, acc1, 0, 0, 0);
            acc2 = __builtin_amdgcn_mfma_f32_16x16x32_bf16(pa0, v4, acc2, 0, 0, 0);
            acc2 = __builtin_amdgcn_mfma_f32_16x16x32_bf16(pa1, v5, acc2, 0, 0, 0);
            acc3 = __builtin_amdgcn_mfma_f32_16x16x32_bf16(pa0, v6, acc3, 0, 0, 0);
            acc3 = __builtin_amdgcn_mfma_f32_16x16x32_bf16(pa1, v7, acc3, 0, 0, 0);
            __builtin_amdgcn_s_setprio(0);

            if (kt < T) stageWrite(lds[cur ^ 1]);   // vmcnt wait lands here
            __syncthreads();
            cur ^= 1;
        }

        den += __shfl_xor(den, 16);
        den += __shfl_xor(den, 32);
        float inv[4];
        #pragma unroll
        for (int r = 0; r < 4; ++r) inv[r] = 1.0f / __shfl(den, lhi * 4 + r);

        float* ob = out + ((size_t)h * 1024 + sigma * 16) * 64;
        #pragma unroll
        for (int r = 0; r < 4; ++r) {
            ob[(lhi * 4 + r) * 64 +  0 + l15] = acc0[r] * inv[r];
            ob[(lhi * 4 + r) * 64 + 16 + l15] = acc1[r] * inv[r];
            ob[(lhi * 4 + r) * 64 + 32 + l15] = acc2[r] * inv[r];
            ob[(lhi * 4 + r) * 64 + 48 + l15] = acc3[r] * inv[r];
        }
    };

    const int s0v = 4 * j + wave;     // 0..31, T = j (uniform in block)
    runStrip(s0v, j);
    runStrip(63 - s0v, 15 - j);       // T = 15-j (uniform in block)
}

// ---------------------------------------------------------------------------
extern "C" void kernel_launch(void* const* d_in, const int* in_sizes, int n_in,
                              void* d_out, int out_size, void* d_ws, size_t ws_size,
                              hipStream_t stream)
{
    const float* q    = (const float*)d_in[0];
    const float* k    = (const float*)d_in[1];
    const float* v    = (const float*)d_in[2];
    const float* proj = (const float*)d_in[3];
    float* out = (float*)d_out;

    char* ws = (char*)d_ws;
    u16* qpw = (u16*)(ws);                                 // 8 MB
    u16* kpw = (u16*)(ws + (size_t)8 * 1024 * 1024);       // 8 MB
    u16* vTw = (u16*)(ws + (size_t)16 * 1024 * 1024);      // 8 MB

    hipLaunchKernelGGL(prep, dim3(3072), dim3(256), 0, stream,
                       q, k, v, proj, qpw, kpw, vTw);
    hipLaunchKernelGGL(attn, dim3(512), dim3(256), 0, stream, qpw, kpw, vTw, out);
}